// Round 1
// baseline (488.917 us; speedup 1.0000x reference)
//
#include <hip/hip_runtime.h>

#define N_NODES 200000
#define N_EDGES 6400000
#define K_BUCKETS 256
#define BUCKET 784          // 256*784 = 200704 >= 200000; dl < 1024
#define NSB 3200            // chunks
#define CHUNK 2000          // NSB*CHUNK == N_EDGES exactly
#define P_SPLIT 8           // blocks per bucket in sagg aggregation
#define M_SPLIT 2           // blocks per bucket in magg (1024-thread blocks)

__device__ __forceinline__ unsigned short f2bf(float x) {
    unsigned u = __float_as_uint(x);
    u += 0x7fffu + ((u >> 16) & 1u);      // RNE to bf16
    return (unsigned short)(u >> 16);
}
__device__ __forceinline__ float bf2f(unsigned short h) {
    return __uint_as_float((unsigned)h << 16);
}

// ---------------- fast path ----------------

// per-chunk bucket histogram, layout counts[sb*K + k]  (coalesced store)
__global__ __launch_bounds__(256) void hist_kernel(const int* __restrict__ dst,
                                                   int* __restrict__ counts)
{
    __shared__ int cnt[K_BUCKETS];
    int tid = threadIdx.x, sb = blockIdx.x;
    cnt[tid] = 0;
    __syncthreads();
    int e0 = sb * CHUNK;
    for (int i = tid; i < CHUNK; i += 256)
        atomicAdd(&cnt[dst[e0 + i] / BUCKET], 1);
    __syncthreads();
    counts[sb * K_BUCKETS + tid] = cnt[tid];
}

// per-bucket exclusive scan across chunks (strided access, small data)
__global__ __launch_bounds__(256) void scan_cols(const int* __restrict__ counts,
                                                 int* __restrict__ baseRel,
                                                 int* __restrict__ tot)
{
    __shared__ int buf[256];
    __shared__ int carry_s;
    int k = blockIdx.x, tid = threadIdx.x;
    if (tid == 0) carry_s = 0;
    __syncthreads();
    for (int base = 0; base < NSB; base += 256) {
        int idx = base + tid;
        int v = (idx < NSB) ? counts[idx * K_BUCKETS + k] : 0;
        buf[tid] = v;
        __syncthreads();
        for (int off = 1; off < 256; off <<= 1) {
            int t = (tid >= off) ? buf[tid - off] : 0;
            __syncthreads();
            buf[tid] += t;
            __syncthreads();
        }
        int incl = buf[tid];
        if (idx < NSB) baseRel[idx * K_BUCKETS + k] = carry_s + incl - v;
        __syncthreads();
        if (tid == 255) carry_s += incl;
        __syncthreads();
    }
    if (tid == 255) tot[k] = carry_s;
}

__global__ __launch_bounds__(256) void scan_tot(const int* __restrict__ tot,
                                                int* __restrict__ bstart)
{
    __shared__ int buf[256];
    int tid = threadIdx.x;
    int v = tot[tid];
    buf[tid] = v;
    __syncthreads();
    for (int off = 1; off < 256; off <<= 1) {
        int t = (tid >= off) ? buf[tid - off] : 0;
        __syncthreads();
        buf[tid] += t;
        __syncthreads();
    }
    bstart[tid] = buf[tid] - v;
    if (tid == 255) bstart[256] = buf[255];
}

// counting-sort scatter: counts pre-loaded (no count pass); permutation in LDS;
// coalesced outputs packedA (int), c01a (uint: c0|c1<<16), c2a (ushort).
__global__ __launch_bounds__(256) void scatter_kernel(
    const int* __restrict__ src, const int* __restrict__ dst,
    const float* __restrict__ r, const float* __restrict__ r_hat,
    const float* __restrict__ W, const float* __restrict__ b,
    const int* __restrict__ counts, const int* __restrict__ baseRel,
    const int* __restrict__ bstart,
    int* __restrict__ packedA, unsigned* __restrict__ c01a,
    unsigned short* __restrict__ c2a)
{
    __shared__ int cur[K_BUCKETS];
    __shared__ int delta[K_BUCKETS];
    __shared__ int scanbuf[256];
    __shared__ int            lpack[CHUNK];
    __shared__ unsigned       lc01[CHUNK];
    __shared__ unsigned short lc2[CHUNK];
    __shared__ unsigned char  skb[CHUNK];

    int tid = threadIdx.x, sb = blockIdx.x;

    // load per-chunk counts (computed by hist) — replaces a whole count pass
    int v = counts[sb * K_BUCKETS + tid];
    scanbuf[tid] = v;
    __syncthreads();
    for (int off = 1; off < 256; off <<= 1) {
        int t = (tid >= off) ? scanbuf[tid - off] : 0;
        __syncthreads();
        scanbuf[tid] += t;
        __syncthreads();
    }
    int localBase = scanbuf[tid] - v;
    int gBase = bstart[tid] + baseRel[sb * K_BUCKETS + tid];
    delta[tid] = gBase - localBase;
    cur[tid] = localBase;
    __syncthreads();

    float w8_0 = W[8],  w9_0 = W[9],  w10_0 = W[10], w11_0 = W[11], b0 = b[0];
    float w8_1 = W[20], w9_1 = W[21], w10_1 = W[22], w11_1 = W[23], b1 = b[1];
    float w8_2 = W[32], w9_2 = W[33], w10_2 = W[34], w11_2 = W[35], b2 = b[2];

    int e0 = sb * CHUNK;
    // pass B: coalesced global reads, scattered LDS writes to sorted slot
    for (int i = tid; i < CHUNK; i += 256) {
        int e = e0 + i;
        int d = dst[e];
        int k = d / BUCKET;
        int dl = d - k * BUCKET;
        int slot = atomicAdd(&cur[k], 1);
        int sn = src[e];
        float rv = r[e];
        size_t he = 3 * (size_t)e;
        float h0 = r_hat[he], h1 = r_hat[he + 1], h2 = r_hat[he + 2];
        lpack[slot] = (sn << 10) | dl;
        unsigned cc0 = f2bf(w8_0 * rv + w9_0 * h0 + w10_0 * h1 + w11_0 * h2 + b0);
        unsigned cc1 = f2bf(w8_1 * rv + w9_1 * h0 + w10_1 * h1 + w11_1 * h2 + b1);
        lc01[slot] = cc0 | (cc1 << 16);
        lc2[slot]  = f2bf(w8_2 * rv + w9_2 * h0 + w10_2 * h1 + w11_2 * h2 + b2);
        skb[slot]  = (unsigned char)k;
    }
    __syncthreads();

    // pass C: sequential LDS reads, coalesced global stores
    for (int s = tid; s < CHUNK; s += 256) {
        int k = skb[s];
        int gpos = delta[k] + s;
        packedA[gpos] = lpack[s];
        c01a[gpos] = lc01[s];
        c2a[gpos]  = lc2[s];
    }
}

// combined layer-independent aggregation:
//   M_i[d] = sum_{e->d} (a_i . z0[src_e] + c_i(e))  for i = 0,1,2
//   cnt[d] = indeg[d]
// one sweep over sorted edges; partial layout [4][M_SPLIT*K][BUCKET]
__global__ __launch_bounds__(1024) void magg_kernel(
    const int* __restrict__ packedA, const unsigned* __restrict__ c01a,
    const unsigned short* __restrict__ c2a, const int* __restrict__ bstart,
    const float4* __restrict__ z0, const float* __restrict__ W,
    float* __restrict__ partial)
{
    __shared__ float m0[BUCKET], m1[BUCKET], m2[BUCKET], csl[BUCKET];
    int tid = threadIdx.x, blk = blockIdx.x;
    int k = blk >> 1;          // bucket (M_SPLIT == 2)
    int p = blk & 1;
    for (int i = tid; i < BUCKET; i += 1024) {
        m0[i] = 0.0f; m1[i] = 0.0f; m2[i] = 0.0f; csl[i] = 0.0f;
    }
    __syncthreads();

    float a00 = W[0],  a01 = W[1],  a02 = W[2],  a03 = W[3];
    float a10 = W[12], a11 = W[13], a12 = W[14], a13 = W[15];
    float a20 = W[24], a21 = W[25], a22 = W[26], a23 = W[27];

    int estart = bstart[k], eend = bstart[k + 1];
    int len = eend - estart;
    int per = (len + M_SPLIT - 1) / M_SPLIT;
    int lo = estart + p * per;
    int hi = min(lo + per, eend);

    for (int j = lo + tid; j < hi; j += 1024) {
        int pack = packedA[j];
        int s = pack >> 10;
        int dl = pack & 1023;
        float4 zs = z0[s];
        unsigned cc = c01a[j];
        unsigned short c2 = c2a[j];
        float v0 = a00 * zs.x + a01 * zs.y + a02 * zs.z + a03 * zs.w
                 + bf2f((unsigned short)(cc & 0xffffu));
        float v1 = a10 * zs.x + a11 * zs.y + a12 * zs.z + a13 * zs.w
                 + bf2f((unsigned short)(cc >> 16));
        float v2 = a20 * zs.x + a21 * zs.y + a22 * zs.z + a23 * zs.w
                 + bf2f(c2);
        atomicAdd(&m0[dl], v0);
        atomicAdd(&m1[dl], v1);
        atomicAdd(&m2[dl], v2);
        atomicAdd(&csl[dl], 1.0f);
    }
    __syncthreads();

    const size_t AS = (size_t)(M_SPLIT * K_BUCKETS) * BUCKET;
    float* base = partial + (size_t)blk * BUCKET;
    for (int i = tid; i < BUCKET; i += 1024) {
        base[i]          = m0[i];
        base[AS + i]     = m1[i];
        base[2 * AS + i] = m2[i];
        base[3 * AS + i] = csl[i];
    }
}

// finalize layer 0: S0 = M0 + indeg * (q0 . z0); stash M1, M2, indeg dense
__global__ __launch_bounds__(256) void fin0_kernel(
    const float4* __restrict__ z0, const float* __restrict__ partial,
    const float* __restrict__ W,
    float* __restrict__ S0, float* __restrict__ M1d,
    float* __restrict__ M2d, float* __restrict__ cntd)
{
    int n = blockIdx.x * 256 + threadIdx.x;
    if (n >= N_NODES) return;
    int k = n / BUCKET;
    int i = n - k * BUCKET;
    const size_t AS = (size_t)(M_SPLIT * K_BUCKETS) * BUCKET;
    const float* p0 = partial + (size_t)(M_SPLIT * k) * BUCKET + i;
    float M0 = p0[0]          + p0[BUCKET];
    float M1 = p0[AS]         + p0[AS + BUCKET];
    float M2 = p0[2 * AS]     + p0[2 * AS + BUCKET];
    float C  = p0[3 * AS]     + p0[3 * AS + BUCKET];
    float4 zv = z0[n];
    float v0 = W[4] * zv.x + W[5] * zv.y + W[6] * zv.z + W[7] * zv.w;
    S0[n]   = M0 + C * v0;
    M1d[n]  = M1;
    M2d[n]  = M2;
    cntd[n] = C;
}

// per-layer graph pass: GS[d] = sum_{e->d} S[src_e]; partial layout [blk][BUCKET]
__global__ __launch_bounds__(256) void sagg_kernel(
    const int* __restrict__ packedA, const int* __restrict__ bstart,
    const float* __restrict__ S, float* __restrict__ partial)
{
    __shared__ float aggsl[BUCKET];
    int tid = threadIdx.x, blk = blockIdx.x;
    int k = blk / P_SPLIT;
    int p = blk - k * P_SPLIT;
    for (int i = tid; i < BUCKET; i += 256) aggsl[i] = 0.0f;
    __syncthreads();

    int estart = bstart[k], eend = bstart[k + 1];
    int len = eend - estart;
    int per = (len + P_SPLIT - 1) / P_SPLIT;
    int lo = estart + p * per;
    int hi = min(lo + per, eend);

    for (int j = lo + tid; j < hi; j += 256) {
        int pack = packedA[j];
        atomicAdd(&aggsl[pack & 1023], S[pack >> 10]);
    }
    __syncthreads();

    float* out = partial + (size_t)blk * BUCKET;
    for (int i = tid; i < BUCKET; i += 256) out[i] = aggsl[i];
}

// finalize layer 1 or 2:
//   S = Sprev + Md + A*GS + cnt*(q.z0 + B*Sprev)
//   layer 2 additionally writes z_out = z0 + S and x_out = z0
__global__ __launch_bounds__(256) void finL_kernel(
    const float4* __restrict__ z0, const float* __restrict__ partial,
    const float* __restrict__ Wl,
    const float* __restrict__ Sprev, const float* __restrict__ Md,
    const float* __restrict__ cntd, int final_layer,
    float* __restrict__ Sout, float4* __restrict__ z_out,
    float4* __restrict__ x_out)
{
    int n = blockIdx.x * 256 + threadIdx.x;
    if (n >= N_NODES) return;
    int k = n / BUCKET;
    int i = n - k * BUCKET;
    float GS = 0.0f;
    const float* pk = partial + (size_t)k * P_SPLIT * BUCKET + i;
#pragma unroll
    for (int p = 0; p < P_SPLIT; ++p) GS += pk[(size_t)p * BUCKET];

    float A = Wl[0] + Wl[1] + Wl[2] + Wl[3];
    float B = Wl[4] + Wl[5] + Wl[6] + Wl[7];
    float4 zv = z0[n];
    float vh = Wl[4] * zv.x + Wl[5] * zv.y + Wl[6] * zv.z + Wl[7] * zv.w;
    float Sp = Sprev[n];
    float C  = cntd[n];
    float S  = Sp + Md[n] + A * GS + C * (vh + B * Sp);
    if (!final_layer) {
        Sout[n] = S;
    } else {
        float4 zo = zv;                 // x = original z0
        zv.x += S; zv.y += S; zv.z += S; zv.w += S;
        z_out[n] = zv;
        x_out[n] = zo;
    }
}

// ---------------- fallback (round-2) ----------------

__global__ __launch_bounds__(256) void init_kernel(
    const float4* __restrict__ z_in, float4* __restrict__ z_cur,
    float4* __restrict__ x_out, float* __restrict__ agg)
{
    int n = blockIdx.x * blockDim.x + threadIdx.x;
    if (n < N_NODES) {
        float4 vv = z_in[n];
        z_cur[n] = vv; x_out[n] = vv; agg[n] = 0.0f;
    }
}

__global__ __launch_bounds__(256) void edge_kernel(
    const float* __restrict__ z, const float* __restrict__ r,
    const float* __restrict__ r_hat, const int* __restrict__ src,
    const int* __restrict__ dst, const float* __restrict__ Wl,
    const float* __restrict__ bl, float* __restrict__ agg)
{
    int e = blockIdx.x * blockDim.x + threadIdx.x;
    if (e >= N_EDGES) return;
    float w0 = Wl[0], w1 = Wl[1], w2 = Wl[2], w3 = Wl[3];
    float w4 = Wl[4], w5 = Wl[5], w6 = Wl[6], w7 = Wl[7];
    float w8 = Wl[8], w9 = Wl[9], w10 = Wl[10], w11 = Wl[11];
    float bias = bl[0];
    int s = src[e], d = dst[e];
    float4 zs = ((const float4*)z)[s];
    float4 zd = ((const float4*)z)[d];
    float rv = r[e];
    const float* rh = r_hat + 3 * (size_t)e;
    float msg = w0*zs.x + w1*zs.y + w2*zs.z + w3*zs.w
              + w4*zd.x + w5*zd.y + w6*zd.z + w7*zd.w
              + w8*rv + w9*rh[0] + w10*rh[1] + w11*rh[2] + bias;
    unsafeAtomicAdd(&agg[d], msg);
}

__global__ __launch_bounds__(256) void node_update(float4* __restrict__ z_cur,
                                                   float* __restrict__ agg)
{
    int n = blockIdx.x * blockDim.x + threadIdx.x;
    if (n < N_NODES) {
        float a = agg[n]; float4 vv = z_cur[n];
        vv.x += a; vv.y += a; vv.z += a; vv.w += a;
        z_cur[n] = vv; agg[n] = 0.0f;
    }
}

__global__ __launch_bounds__(256) void final_update(const float4* __restrict__ z_cur,
                                                    const float* __restrict__ agg,
                                                    float4* __restrict__ z_out)
{
    int n = blockIdx.x * blockDim.x + threadIdx.x;
    if (n < N_NODES) {
        float a = agg[n]; float4 vv = z_cur[n];
        vv.x += a; vv.y += a; vv.z += a; vv.w += a;
        z_out[n] = vv;
    }
}

// ---------------- launch ----------------

extern "C" void kernel_launch(void* const* d_in, const int* in_sizes, int n_in,
                              void* d_out, int out_size, void* d_ws, size_t ws_size,
                              hipStream_t stream)
{
    const float* z     = (const float*)d_in[0];
    const float* r     = (const float*)d_in[1];
    const float* r_hat = (const float*)d_in[2];
    const float* W     = (const float*)d_in[3];
    const float* b     = (const float*)d_in[4];
    const int*   src   = (const int*)d_in[5];
    const int*   dst   = (const int*)d_in[6];
    float* out = (float*)d_out;

    char* ws = (char*)d_ws;
    size_t off = 0;
    auto alloc = [&](size_t bytes) {
        void* p = ws + off;
        off += (bytes + 15) & ~(size_t)15;
        return p;
    };
    int*            packedA = (int*)alloc((size_t)N_EDGES * 4);
    unsigned*       c01a    = (unsigned*)alloc((size_t)N_EDGES * 4);
    unsigned short* c2a     = (unsigned short*)alloc((size_t)N_EDGES * 2);
    int*            counts  = (int*)alloc((size_t)NSB * K_BUCKETS * 4);
    int*            baseRel = (int*)alloc((size_t)NSB * K_BUCKETS * 4);
    int*            tot     = (int*)alloc((size_t)K_BUCKETS * 4);
    int*            bstart  = (int*)alloc((size_t)(K_BUCKETS + 1) * 4);
    float*          S0      = (float*)alloc((size_t)N_NODES * 4);
    float*          S1M1    = (float*)alloc((size_t)N_NODES * 4);  // M1, then S1
    float*          M2d     = (float*)alloc((size_t)N_NODES * 4);
    float*          cntd    = (float*)alloc((size_t)N_NODES * 4);
    // shared by magg (4 planes x 512 blocks) and sagg (2048 blocks) — same bytes
    float*          partial = (float*)alloc((size_t)K_BUCKETS * P_SPLIT * BUCKET * 4);
    size_t required = off;

    dim3 nblk((N_NODES + 255) / 256);

    if (ws_size >= required) {
        hist_kernel<<<NSB, 256, 0, stream>>>(dst, counts);
        scan_cols<<<K_BUCKETS, 256, 0, stream>>>(counts, baseRel, tot);
        scan_tot<<<1, 256, 0, stream>>>(tot, bstart);
        scatter_kernel<<<NSB, 256, 0, stream>>>(src, dst, r, r_hat, W, b,
                                                counts, baseRel, bstart,
                                                packedA, c01a, c2a);
        // one combined pass: M0, M1, M2, indeg
        magg_kernel<<<M_SPLIT * K_BUCKETS, 1024, 0, stream>>>(
            packedA, c01a, c2a, bstart, (const float4*)z, W, partial);
        fin0_kernel<<<nblk, 256, 0, stream>>>(
            (const float4*)z, partial, W, S0, S1M1, M2d, cntd);
        // layer 1: GS0 then finalize
        sagg_kernel<<<K_BUCKETS * P_SPLIT, 256, 0, stream>>>(
            packedA, bstart, S0, partial);
        finL_kernel<<<nblk, 256, 0, stream>>>(
            (const float4*)z, partial, W + 12, S0, S1M1, cntd, 0,
            S1M1, (float4*)out, (float4*)(out + 4 * (size_t)N_NODES));
        // layer 2: GS1 then finalize (writes z_out and x_out)
        sagg_kernel<<<K_BUCKETS * P_SPLIT, 256, 0, stream>>>(
            packedA, bstart, S1M1, partial);
        finL_kernel<<<nblk, 256, 0, stream>>>(
            (const float4*)z, partial, W + 24, S1M1, M2d, cntd, 1,
            S0 /*unused*/, (float4*)out, (float4*)(out + 4 * (size_t)N_NODES));
    } else {
        // fallback: round-2 path
        float* agg   = (float*)d_ws;
        float* z_cur = agg + N_NODES;
        dim3 eblk((N_EDGES + 255) / 256);
        init_kernel<<<nblk, 256, 0, stream>>>(
            (const float4*)z, (float4*)z_cur,
            (float4*)(out + 4 * (size_t)N_NODES), agg);
        for (int i = 0; i < 3; ++i) {
            edge_kernel<<<eblk, 256, 0, stream>>>(
                z_cur, r, r_hat, src, dst, W + 12 * i, b + i, agg);
            if (i < 2)
                node_update<<<nblk, 256, 0, stream>>>((float4*)z_cur, agg);
            else
                final_update<<<nblk, 256, 0, stream>>>(
                    (const float4*)z_cur, agg, (float4*)out);
        }
    }
}

// Round 2
// 462.237 us; speedup vs baseline: 1.0577x; 1.0577x over previous
//
#include <hip/hip_runtime.h>

#define N_NODES 200000
#define N_EDGES 6400000
#define K_BUCKETS 256
#define BUCKET 784          // 256*784 = 200704 >= 200000; dl < 1024
#define NSB 3200            // chunks
#define CHUNK 2000          // NSB*CHUNK == N_EDGES exactly
#define P_SPLIT 8           // blocks per bucket in sagg aggregation
#define M_SPLIT 2           // blocks per bucket in magg (1024-thread blocks)

__device__ __forceinline__ unsigned short f2bf(float x) {
    unsigned u = __float_as_uint(x);
    u += 0x7fffu + ((u >> 16) & 1u);      // RNE to bf16
    return (unsigned short)(u >> 16);
}
__device__ __forceinline__ float bf2f(unsigned short h) {
    return __uint_as_float((unsigned)h << 16);
}

// ---------------- fast path ----------------

// per-chunk bucket histogram, layout counts[sb*K + k]  (coalesced store)
__global__ __launch_bounds__(256) void hist_kernel(const int* __restrict__ dst,
                                                   int* __restrict__ counts)
{
    __shared__ int cnt[K_BUCKETS];
    int tid = threadIdx.x, sb = blockIdx.x;
    cnt[tid] = 0;
    __syncthreads();
    int e0 = sb * CHUNK;
    for (int i = tid; i < CHUNK; i += 256)
        atomicAdd(&cnt[dst[e0 + i] / BUCKET], 1);
    __syncthreads();
    counts[sb * K_BUCKETS + tid] = cnt[tid];
}

// per-bucket exclusive scan across chunks (strided access, small data)
__global__ __launch_bounds__(256) void scan_cols(const int* __restrict__ counts,
                                                 int* __restrict__ baseRel,
                                                 int* __restrict__ tot)
{
    __shared__ int buf[256];
    __shared__ int carry_s;
    int k = blockIdx.x, tid = threadIdx.x;
    if (tid == 0) carry_s = 0;
    __syncthreads();
    for (int base = 0; base < NSB; base += 256) {
        int idx = base + tid;
        int v = (idx < NSB) ? counts[idx * K_BUCKETS + k] : 0;
        buf[tid] = v;
        __syncthreads();
        for (int off = 1; off < 256; off <<= 1) {
            int t = (tid >= off) ? buf[tid - off] : 0;
            __syncthreads();
            buf[tid] += t;
            __syncthreads();
        }
        int incl = buf[tid];
        if (idx < NSB) baseRel[idx * K_BUCKETS + k] = carry_s + incl - v;
        __syncthreads();
        if (tid == 255) carry_s += incl;
        __syncthreads();
    }
    if (tid == 255) tot[k] = carry_s;
}

__global__ __launch_bounds__(256) void scan_tot(const int* __restrict__ tot,
                                                int* __restrict__ bstart)
{
    __shared__ int buf[256];
    int tid = threadIdx.x;
    int v = tot[tid];
    buf[tid] = v;
    __syncthreads();
    for (int off = 1; off < 256; off <<= 1) {
        int t = (tid >= off) ? buf[tid - off] : 0;
        __syncthreads();
        buf[tid] += t;
        __syncthreads();
    }
    bstart[tid] = buf[tid] - v;
    if (tid == 255) bstart[256] = buf[255];
}

// counting-sort scatter: counts pre-loaded (no count pass); permutation in LDS;
// coalesced outputs packedA (int), c01a (uint: c0|c1<<16), c2a (ushort).
__global__ __launch_bounds__(256) void scatter_kernel(
    const int* __restrict__ src, const int* __restrict__ dst,
    const float* __restrict__ r, const float* __restrict__ r_hat,
    const float* __restrict__ W, const float* __restrict__ b,
    const int* __restrict__ counts, const int* __restrict__ baseRel,
    const int* __restrict__ bstart,
    int* __restrict__ packedA, unsigned* __restrict__ c01a,
    unsigned short* __restrict__ c2a)
{
    __shared__ int cur[K_BUCKETS];
    __shared__ int delta[K_BUCKETS];
    __shared__ int scanbuf[256];
    __shared__ int            lpack[CHUNK];
    __shared__ unsigned       lc01[CHUNK];
    __shared__ unsigned short lc2[CHUNK];
    __shared__ unsigned char  skb[CHUNK];

    int tid = threadIdx.x, sb = blockIdx.x;

    // load per-chunk counts (computed by hist) — replaces a whole count pass
    int v = counts[sb * K_BUCKETS + tid];
    scanbuf[tid] = v;
    __syncthreads();
    for (int off = 1; off < 256; off <<= 1) {
        int t = (tid >= off) ? scanbuf[tid - off] : 0;
        __syncthreads();
        scanbuf[tid] += t;
        __syncthreads();
    }
    int localBase = scanbuf[tid] - v;
    int gBase = bstart[tid] + baseRel[sb * K_BUCKETS + tid];
    delta[tid] = gBase - localBase;
    cur[tid] = localBase;
    __syncthreads();

    float w8_0 = W[8],  w9_0 = W[9],  w10_0 = W[10], w11_0 = W[11], b0 = b[0];
    float w8_1 = W[20], w9_1 = W[21], w10_1 = W[22], w11_1 = W[23], b1 = b[1];
    float w8_2 = W[32], w9_2 = W[33], w10_2 = W[34], w11_2 = W[35], b2 = b[2];

    int e0 = sb * CHUNK;
    // pass B: coalesced global reads, scattered LDS writes to sorted slot
    for (int i = tid; i < CHUNK; i += 256) {
        int e = e0 + i;
        int d = dst[e];
        int k = d / BUCKET;
        int dl = d - k * BUCKET;
        int slot = atomicAdd(&cur[k], 1);
        int sn = src[e];
        float rv = r[e];
        size_t he = 3 * (size_t)e;
        float h0 = r_hat[he], h1 = r_hat[he + 1], h2 = r_hat[he + 2];
        lpack[slot] = (sn << 10) | dl;
        unsigned cc0 = f2bf(w8_0 * rv + w9_0 * h0 + w10_0 * h1 + w11_0 * h2 + b0);
        unsigned cc1 = f2bf(w8_1 * rv + w9_1 * h0 + w10_1 * h1 + w11_1 * h2 + b1);
        lc01[slot] = cc0 | (cc1 << 16);
        lc2[slot]  = f2bf(w8_2 * rv + w9_2 * h0 + w10_2 * h1 + w11_2 * h2 + b2);
        skb[slot]  = (unsigned char)k;
    }
    __syncthreads();

    // pass C: sequential LDS reads, coalesced global stores
    for (int s = tid; s < CHUNK; s += 256) {
        int k = skb[s];
        int gpos = delta[k] + s;
        packedA[gpos] = lpack[s];
        c01a[gpos] = lc01[s];
        c2a[gpos]  = lc2[s];
    }
}

// combined layer-independent aggregation:
//   M_i[d] = sum_{e->d} (a_i . z0[src_e] + c_i(e))  for i = 0,1,2
//   cnt[d] = indeg[d]
// one sweep over sorted edges; partial layout [4][M_SPLIT*K][BUCKET]
// NOTE: unsafeAtomicAdd -> native ds_add_f32 (plain atomicAdd(float*) is a
// CAS retry loop on LDS — 2+ dependent ~120cy LDS round-trips per add, the
// latency wall measured in R1). Count uses native int ds_add_u32.
__global__ __launch_bounds__(1024) void magg_kernel(
    const int* __restrict__ packedA, const unsigned* __restrict__ c01a,
    const unsigned short* __restrict__ c2a, const int* __restrict__ bstart,
    const float4* __restrict__ z0, const float* __restrict__ W,
    float* __restrict__ partial)
{
    __shared__ float m0[BUCKET], m1[BUCKET], m2[BUCKET];
    __shared__ int   ccnt[BUCKET];
    int tid = threadIdx.x, blk = blockIdx.x;
    int k = blk >> 1;          // bucket (M_SPLIT == 2)
    int p = blk & 1;
    for (int i = tid; i < BUCKET; i += 1024) {
        m0[i] = 0.0f; m1[i] = 0.0f; m2[i] = 0.0f; ccnt[i] = 0;
    }
    __syncthreads();

    float a00 = W[0],  a01 = W[1],  a02 = W[2],  a03 = W[3];
    float a10 = W[12], a11 = W[13], a12 = W[14], a13 = W[15];
    float a20 = W[24], a21 = W[25], a22 = W[26], a23 = W[27];

    int estart = bstart[k], eend = bstart[k + 1];
    int len = eend - estart;
    int per = (len + M_SPLIT - 1) / M_SPLIT;
    int lo = estart + p * per;
    int hi = min(lo + per, eend);

    for (int j = lo + tid; j < hi; j += 1024) {
        int pack = packedA[j];
        int s = pack >> 10;
        int dl = pack & 1023;
        float4 zs = z0[s];
        unsigned cc = c01a[j];
        unsigned short c2 = c2a[j];
        float v0 = a00 * zs.x + a01 * zs.y + a02 * zs.z + a03 * zs.w
                 + bf2f((unsigned short)(cc & 0xffffu));
        float v1 = a10 * zs.x + a11 * zs.y + a12 * zs.z + a13 * zs.w
                 + bf2f((unsigned short)(cc >> 16));
        float v2 = a20 * zs.x + a21 * zs.y + a22 * zs.z + a23 * zs.w
                 + bf2f(c2);
        unsafeAtomicAdd(&m0[dl], v0);
        unsafeAtomicAdd(&m1[dl], v1);
        unsafeAtomicAdd(&m2[dl], v2);
        atomicAdd(&ccnt[dl], 1);
    }
    __syncthreads();

    const size_t AS = (size_t)(M_SPLIT * K_BUCKETS) * BUCKET;
    float* base = partial + (size_t)blk * BUCKET;
    for (int i = tid; i < BUCKET; i += 1024) {
        base[i]          = m0[i];
        base[AS + i]     = m1[i];
        base[2 * AS + i] = m2[i];
        base[3 * AS + i] = (float)ccnt[i];
    }
}

// finalize layer 0: S0 = M0 + indeg * (q0 . z0); stash M1, M2, indeg dense
__global__ __launch_bounds__(256) void fin0_kernel(
    const float4* __restrict__ z0, const float* __restrict__ partial,
    const float* __restrict__ W,
    float* __restrict__ S0, float* __restrict__ M1d,
    float* __restrict__ M2d, float* __restrict__ cntd)
{
    int n = blockIdx.x * 256 + threadIdx.x;
    if (n >= N_NODES) return;
    int k = n / BUCKET;
    int i = n - k * BUCKET;
    const size_t AS = (size_t)(M_SPLIT * K_BUCKETS) * BUCKET;
    const float* p0 = partial + (size_t)(M_SPLIT * k) * BUCKET + i;
    float M0 = p0[0]          + p0[BUCKET];
    float M1 = p0[AS]         + p0[AS + BUCKET];
    float M2 = p0[2 * AS]     + p0[2 * AS + BUCKET];
    float C  = p0[3 * AS]     + p0[3 * AS + BUCKET];
    float4 zv = z0[n];
    float v0 = W[4] * zv.x + W[5] * zv.y + W[6] * zv.z + W[7] * zv.w;
    S0[n]   = M0 + C * v0;
    M1d[n]  = M1;
    M2d[n]  = M2;
    cntd[n] = C;
}

// per-layer graph pass: GS[d] = sum_{e->d} S[src_e]; partial layout [blk][BUCKET]
__global__ __launch_bounds__(256) void sagg_kernel(
    const int* __restrict__ packedA, const int* __restrict__ bstart,
    const float* __restrict__ S, float* __restrict__ partial)
{
    __shared__ float aggsl[BUCKET];
    int tid = threadIdx.x, blk = blockIdx.x;
    int k = blk / P_SPLIT;
    int p = blk - k * P_SPLIT;
    for (int i = tid; i < BUCKET; i += 256) aggsl[i] = 0.0f;
    __syncthreads();

    int estart = bstart[k], eend = bstart[k + 1];
    int len = eend - estart;
    int per = (len + P_SPLIT - 1) / P_SPLIT;
    int lo = estart + p * per;
    int hi = min(lo + per, eend);

    for (int j = lo + tid; j < hi; j += 256) {
        int pack = packedA[j];
        unsafeAtomicAdd(&aggsl[pack & 1023], S[pack >> 10]);   // ds_add_f32
    }
    __syncthreads();

    float* out = partial + (size_t)blk * BUCKET;
    for (int i = tid; i < BUCKET; i += 256) out[i] = aggsl[i];
}

// finalize layer 1 or 2:
//   S = Sprev + Md + A*GS + cnt*(q.z0 + B*Sprev)
//   layer 2 additionally writes z_out = z0 + S and x_out = z0
__global__ __launch_bounds__(256) void finL_kernel(
    const float4* __restrict__ z0, const float* __restrict__ partial,
    const float* __restrict__ Wl,
    const float* __restrict__ Sprev, const float* __restrict__ Md,
    const float* __restrict__ cntd, int final_layer,
    float* __restrict__ Sout, float4* __restrict__ z_out,
    float4* __restrict__ x_out)
{
    int n = blockIdx.x * 256 + threadIdx.x;
    if (n >= N_NODES) return;
    int k = n / BUCKET;
    int i = n - k * BUCKET;
    float GS = 0.0f;
    const float* pk = partial + (size_t)k * P_SPLIT * BUCKET + i;
#pragma unroll
    for (int p = 0; p < P_SPLIT; ++p) GS += pk[(size_t)p * BUCKET];

    float A = Wl[0] + Wl[1] + Wl[2] + Wl[3];
    float B = Wl[4] + Wl[5] + Wl[6] + Wl[7];
    float4 zv = z0[n];
    float vh = Wl[4] * zv.x + Wl[5] * zv.y + Wl[6] * zv.z + Wl[7] * zv.w;
    float Sp = Sprev[n];
    float C  = cntd[n];
    float S  = Sp + Md[n] + A * GS + C * (vh + B * Sp);
    if (!final_layer) {
        Sout[n] = S;
    } else {
        float4 zo = zv;                 // x = original z0
        zv.x += S; zv.y += S; zv.z += S; zv.w += S;
        z_out[n] = zv;
        x_out[n] = zo;
    }
}

// ---------------- fallback (round-2) ----------------

__global__ __launch_bounds__(256) void init_kernel(
    const float4* __restrict__ z_in, float4* __restrict__ z_cur,
    float4* __restrict__ x_out, float* __restrict__ agg)
{
    int n = blockIdx.x * blockDim.x + threadIdx.x;
    if (n < N_NODES) {
        float4 vv = z_in[n];
        z_cur[n] = vv; x_out[n] = vv; agg[n] = 0.0f;
    }
}

__global__ __launch_bounds__(256) void edge_kernel(
    const float* __restrict__ z, const float* __restrict__ r,
    const float* __restrict__ r_hat, const int* __restrict__ src,
    const int* __restrict__ dst, const float* __restrict__ Wl,
    const float* __restrict__ bl, float* __restrict__ agg)
{
    int e = blockIdx.x * blockDim.x + threadIdx.x;
    if (e >= N_EDGES) return;
    float w0 = Wl[0], w1 = Wl[1], w2 = Wl[2], w3 = Wl[3];
    float w4 = Wl[4], w5 = Wl[5], w6 = Wl[6], w7 = Wl[7];
    float w8 = Wl[8], w9 = Wl[9], w10 = Wl[10], w11 = Wl[11];
    float bias = bl[0];
    int s = src[e], d = dst[e];
    float4 zs = ((const float4*)z)[s];
    float4 zd = ((const float4*)z)[d];
    float rv = r[e];
    const float* rh = r_hat + 3 * (size_t)e;
    float msg = w0*zs.x + w1*zs.y + w2*zs.z + w3*zs.w
              + w4*zd.x + w5*zd.y + w6*zd.z + w7*zd.w
              + w8*rv + w9*rh[0] + w10*rh[1] + w11*rh[2] + bias;
    unsafeAtomicAdd(&agg[d], msg);
}

__global__ __launch_bounds__(256) void node_update(float4* __restrict__ z_cur,
                                                   float* __restrict__ agg)
{
    int n = blockIdx.x * blockDim.x + threadIdx.x;
    if (n < N_NODES) {
        float a = agg[n]; float4 vv = z_cur[n];
        vv.x += a; vv.y += a; vv.z += a; vv.w += a;
        z_cur[n] = vv; agg[n] = 0.0f;
    }
}

__global__ __launch_bounds__(256) void final_update(const float4* __restrict__ z_cur,
                                                    const float* __restrict__ agg,
                                                    float4* __restrict__ z_out)
{
    int n = blockIdx.x * blockDim.x + threadIdx.x;
    if (n < N_NODES) {
        float a = agg[n]; float4 vv = z_cur[n];
        vv.x += a; vv.y += a; vv.z += a; vv.w += a;
        z_out[n] = vv;
    }
}

// ---------------- launch ----------------

extern "C" void kernel_launch(void* const* d_in, const int* in_sizes, int n_in,
                              void* d_out, int out_size, void* d_ws, size_t ws_size,
                              hipStream_t stream)
{
    const float* z     = (const float*)d_in[0];
    const float* r     = (const float*)d_in[1];
    const float* r_hat = (const float*)d_in[2];
    const float* W     = (const float*)d_in[3];
    const float* b     = (const float*)d_in[4];
    const int*   src   = (const int*)d_in[5];
    const int*   dst   = (const int*)d_in[6];
    float* out = (float*)d_out;

    char* ws = (char*)d_ws;
    size_t off = 0;
    auto alloc = [&](size_t bytes) {
        void* p = ws + off;
        off += (bytes + 15) & ~(size_t)15;
        return p;
    };
    int*            packedA = (int*)alloc((size_t)N_EDGES * 4);
    unsigned*       c01a    = (unsigned*)alloc((size_t)N_EDGES * 4);
    unsigned short* c2a     = (unsigned short*)alloc((size_t)N_EDGES * 2);
    int*            counts  = (int*)alloc((size_t)NSB * K_BUCKETS * 4);
    int*            baseRel = (int*)alloc((size_t)NSB * K_BUCKETS * 4);
    int*            tot     = (int*)alloc((size_t)K_BUCKETS * 4);
    int*            bstart  = (int*)alloc((size_t)(K_BUCKETS + 1) * 4);
    float*          S0      = (float*)alloc((size_t)N_NODES * 4);
    float*          S1M1    = (float*)alloc((size_t)N_NODES * 4);  // M1, then S1
    float*          M2d     = (float*)alloc((size_t)N_NODES * 4);
    float*          cntd    = (float*)alloc((size_t)N_NODES * 4);
    // shared by magg (4 planes x 512 blocks) and sagg (2048 blocks) — same bytes
    float*          partial = (float*)alloc((size_t)K_BUCKETS * P_SPLIT * BUCKET * 4);
    size_t required = off;

    dim3 nblk((N_NODES + 255) / 256);

    if (ws_size >= required) {
        hist_kernel<<<NSB, 256, 0, stream>>>(dst, counts);
        scan_cols<<<K_BUCKETS, 256, 0, stream>>>(counts, baseRel, tot);
        scan_tot<<<1, 256, 0, stream>>>(tot, bstart);
        scatter_kernel<<<NSB, 256, 0, stream>>>(src, dst, r, r_hat, W, b,
                                                counts, baseRel, bstart,
                                                packedA, c01a, c2a);
        // one combined pass: M0, M1, M2, indeg
        magg_kernel<<<M_SPLIT * K_BUCKETS, 1024, 0, stream>>>(
            packedA, c01a, c2a, bstart, (const float4*)z, W, partial);
        fin0_kernel<<<nblk, 256, 0, stream>>>(
            (const float4*)z, partial, W, S0, S1M1, M2d, cntd);
        // layer 1: GS0 then finalize
        sagg_kernel<<<K_BUCKETS * P_SPLIT, 256, 0, stream>>>(
            packedA, bstart, S0, partial);
        finL_kernel<<<nblk, 256, 0, stream>>>(
            (const float4*)z, partial, W + 12, S0, S1M1, cntd, 0,
            S1M1, (float4*)out, (float4*)(out + 4 * (size_t)N_NODES));
        // layer 2: GS1 then finalize (writes z_out and x_out)
        sagg_kernel<<<K_BUCKETS * P_SPLIT, 256, 0, stream>>>(
            packedA, bstart, S1M1, partial);
        finL_kernel<<<nblk, 256, 0, stream>>>(
            (const float4*)z, partial, W + 24, S1M1, M2d, cntd, 1,
            S0 /*unused*/, (float4*)out, (float4*)(out + 4 * (size_t)N_NODES));
    } else {
        // fallback: round-2 path
        float* agg   = (float*)d_ws;
        float* z_cur = agg + N_NODES;
        dim3 eblk((N_EDGES + 255) / 256);
        init_kernel<<<nblk, 256, 0, stream>>>(
            (const float4*)z, (float4*)z_cur,
            (float4*)(out + 4 * (size_t)N_NODES), agg);
        for (int i = 0; i < 3; ++i) {
            edge_kernel<<<eblk, 256, 0, stream>>>(
                z_cur, r, r_hat, src, dst, W + 12 * i, b + i, agg);
            if (i < 2)
                node_update<<<nblk, 256, 0, stream>>>((float4*)z_cur, agg);
            else
                final_update<<<nblk, 256, 0, stream>>>(
                    (const float4*)z_cur, agg, (float4*)out);
        }
    }
}